// Round 10
// baseline (134.835 us; speedup 1.0000x reference)
//
#include <hip/hip_runtime.h>
#include <math.h>

#define NB 8
#define NA 32
#define NCELL 256
#define NPAIR 496
#define TC 16             // triplets per chunk
#define XS 20             // padded activation row stride (floats, 16B-aligned)
#define NQ 8              // chunk-slots per cell
#define CUTOFF_F 3.5f
#define EPS_F 1e-7f
#define CLIP_MIN_F 1e-10f
#define PI_F 3.14159274101257324f   // float32(np.pi)

// counted-vmcnt pipeline barrier (T4): keep the newest 4 global_load_lds in
// flight across the barrier; drains the oldest 4 = the slice consumed next.
#define PIPE_BAR4() do { \
    asm volatile("s_waitcnt lgkmcnt(0) vmcnt(4)" ::: "memory"); \
    __builtin_amdgcn_s_barrier(); \
    __builtin_amdgcn_sched_barrier(0); \
} while (0)
#define PIPE_BAR0() do { \
    asm volatile("s_waitcnt lgkmcnt(0) vmcnt(0)" ::: "memory"); \
    __builtin_amdgcn_s_barrier(); \
    __builtin_amdgcn_sched_barrier(0); \
} while (0)

// fast tanh: (e^2ax-1)/(e^2ax+1) with sign reattach; ~1e-7 abs err
__device__ __forceinline__ float fast_tanh(float x) {
    const float ax = fabsf(x);
    const float t = exp2f(fminf(2.8853900817779268f * ax, 30.0f)); // e^{2ax}
    const float r = (t - 1.0f) * __builtin_amdgcn_rcpf(t + 1.0f);
    return __int_as_float((__float_as_int(x) & 0x80000000) | __float_as_int(r));
}

// -------- async global->LDS staging (no VGPR payload) --------
__device__ __forceinline__ void cp_async16(const float* g, float* l) {
    __builtin_amdgcn_global_load_lds(
        (const __attribute__((address_space(1))) unsigned int*)g,
        (__attribute__((address_space(3))) unsigned int*)l, 16, 0, 0);
}

// stage one 4096-float (16KB) slice: 4 issues/thread (vmcnt +4 per wave)
__device__ __forceinline__ void stage16k(const float* __restrict__ g,
                                         float* __restrict__ buf, int tid) {
    const int lane = tid & 63, w = tid >> 6;
#pragma unroll
    for (int r = 0; r < 4; ++r) {
        const int off = (w * 4 + r) * 256;
        cp_async16(g + off + lane * 4, buf + off);   // LDS base wave-uniform
    }
}

// decode upper-triangle pair index p -> (j,k), j<k, row-major over k>j
__device__ __forceinline__ void decode_pair(int p, int& j, int& k) {
    int rem = p; j = 0;
    while (rem >= 31 - j) { rem -= 31 - j; ++j; }
    k = j + 1 + rem;
}

// -------- layer computes (weights from LDS, bias from register) --------
// BOUNDED unroll — full unroll lets the scheduler hoist all ds_reads and
// blow the VGPR file (r4/r5 bug: 256 VGPR -> 1.6GB scratch spill traffic).
template<int K, bool RES>
__device__ __forceinline__ void compute64(
    const float* __restrict__ Wl, float bb,
    const float* __restrict__ X, float* __restrict__ Y,
    const float* __restrict__ R, int tid)
{
    const int fi = tid & 63;
    const int xo = (tid >> 6) * 4;       // wave-uniform -> broadcast reads
    float a0 = bb, a1 = bb, a2 = bb, a3 = bb;
#pragma unroll 4
    for (int k = 0; k < K; ++k) {
        const float4 xv = *(const float4*)&X[k * XS + xo];
        const float w = Wl[k * 64 + fi];
        a0 += xv.x * w; a1 += xv.y * w; a2 += xv.z * w; a3 += xv.w * w;
    }
    float4 y;
    y.x = fast_tanh(a0); y.y = fast_tanh(a1); y.z = fast_tanh(a2); y.w = fast_tanh(a3);
    if (RES) {
        const float4 r = *(const float4*)&R[fi * XS + xo];
        y.x += r.x; y.y += r.y; y.z += r.z; y.w += r.w;
    }
    *(float4*)&Y[fi * XS + xo] = y;
}

// 64->128 layer, one 32-row k-slice. Thread = outputs (fo, fo+64) x 4 triplets.
__device__ __forceinline__ void compute5_part(
    const float* __restrict__ Wl /*32 rows x 128*/, const float* __restrict__ X,
    int k0, float (&a0)[4], float (&a1)[4], int tid)
{
    const int fo = tid & 63;
    const int xo = (tid >> 6) * 4;
#pragma unroll 4
    for (int k = 0; k < 32; ++k) {
        const float4 xv = *(const float4*)&X[(k0 + k) * XS + xo];
        const float w0 = Wl[k * 128 + fo];
        const float w1 = Wl[k * 128 + fo + 64];
        a0[0] += xv.x * w0; a0[1] += xv.y * w0; a0[2] += xv.z * w0; a0[3] += xv.w * w0;
        a1[0] += xv.x * w1; a1[1] += xv.y * w1; a1[2] += xv.z * w1; a1[3] += xv.w * w1;
    }
}

// 128->256 layer, one 16-row k-slice. Thread = output f=tid, all 16 triplets.
__device__ __forceinline__ void compute6_part(
    const float* __restrict__ Wl /*16 rows x 256*/, const float* __restrict__ X,
    float (&a)[16], int tid)
{
#pragma unroll 2
    for (int k = 0; k < 16; ++k) {
        const float w = Wl[k * 256 + tid];
        const float4 x0 = *(const float4*)&X[k * XS + 0];
        const float4 x1 = *(const float4*)&X[k * XS + 4];
        const float4 x2 = *(const float4*)&X[k * XS + 8];
        const float4 x3 = *(const float4*)&X[k * XS + 12];
        a[0]  += x0.x * w; a[1]  += x0.y * w; a[2]  += x0.z * w; a[3]  += x0.w * w;
        a[4]  += x1.x * w; a[5]  += x1.y * w; a[6]  += x1.z * w; a[7]  += x1.w * w;
        a[8]  += x2.x * w; a[9]  += x2.y * w; a[10] += x2.z * w; a[11] += x2.w * w;
        a[12] += x3.x * w; a[13] += x3.y * w; a[14] += x3.z * w; a[15] += x3.w * w;
    }
}

// ---------------- K2: fused feat + MLP (3-buffer counted-vmcnt rotation) -----
// Each (cell,q) block derives its own triplet set from a deterministic
// ballot-built bitmask (identical across NQ siblings), computes features
// in-LDS, runs the pipelined MLP, and writes its partial sum to a PRIVATE
// GAq slot (no atomics, no zero-init kernel).
__global__ __launch_bounds__(256) void aev_mlp(
    const float* __restrict__ D, const float* __restrict__ S,
    const float* __restrict__ W0, const float* __restrict__ b0,
    const float* __restrict__ W1, const float* __restrict__ b1,
    const float* __restrict__ W2, const float* __restrict__ b2,
    const float* __restrict__ W3, const float* __restrict__ b3,
    const float* __restrict__ W4, const float* __restrict__ b4,
    const float* __restrict__ W5, const float* __restrict__ b5,
    const float* __restrict__ W6, const float* __restrict__ b6,
    float* __restrict__ GAq)
{
    __shared__ __align__(16) float WB0[4096];
    __shared__ __align__(16) float WB1[4096];
    __shared__ __align__(16) float WB2[4096];
    __shared__ __align__(16) float W0s[576];
    __shared__ __align__(16) float Dm[NA][NA];
    __shared__ float Sv[NA];
    __shared__ unsigned long long msk[8];
    __shared__ __align__(16) float Xs[9 * XS];
    __shared__ __align__(16) float U0[64 * XS];
    __shared__ __align__(16) float U1[64 * XS];
    __shared__ __align__(16) float U2[64 * XS];
    __shared__ float wsh[TC];

    const int tid = threadIdx.x;
    const int cell = blockIdx.x & 255;   // cell-major: q=0 wave of blocks first
    const int q = blockIdx.x >> 8;
    const int b = cell >> 5, i = cell & 31;
    float* gslot = &GAq[(cell * NQ + q) * 256];

    // ---- load Dm / Sv ----
    for (int idx = tid; idx < NA * NA; idx += 256)
        ((float*)Dm)[idx] = D[b * NA * NA + idx];
    if (tid < NA) Sv[tid] = S[b * NA + tid];
    __syncthreads();

    // ---- deterministic active-pair bitmask (same in every sibling) ----
    {
        int j, k;
        decode_pair(tid, j, k);
        const float dij = Dm[i][j], dik = Dm[i][k];
        const bool f0 = (dij < CUTOFF_F) & (dij != 0.f) & (dik < CUTOFF_F) & (dik != 0.f);
        const unsigned long long m0 = __ballot(f0);
        if ((tid & 63) == 0) msk[tid >> 6] = m0;
        bool f1 = false;
        const int p1 = tid + 256;
        if (p1 < NPAIR) {
            decode_pair(p1, j, k);
            const float a = Dm[i][j], c = Dm[i][k];
            f1 = (a < CUTOFF_F) & (a != 0.f) & (c < CUTOFF_F) & (c != 0.f);
        }
        const unsigned long long m1 = __ballot(f1);
        if ((tid & 63) == 0) msk[4 + (tid >> 6)] = m1;
    }
    __syncthreads();

    int T = 0;
#pragma unroll
    for (int w = 0; w < 8; ++w) T += __popcll(msk[w]);
    const int nch = (T + TC - 1) / TC;
    if (q >= nch) {                 // idle sibling: publish zero partial, exit
        gslot[tid] = 0.f;
        return;
    }

    // loop-invariant per-thread biases (registers, not LDS)
    const int fi64 = tid & 63;
    const float bias0 = b0[fi64];
    const float bias1 = b1[fi64];
    const float bias2 = b2[fi64];
    const float bias3 = b3[fi64];
    const float bias4 = b4[fi64];
    const float bias5a = b5[fi64];
    const float bias5b = b5[fi64 + 64];
    const float bias6 = b6[tid];

    // W0 (2.3KB) staged once per block (covered by first PIPE_BAR4)
    if (tid < 144) ((float4*)W0s)[tid] = ((const float4*)W0)[tid];

    float gacc = 0.f;

    for (int c = q; c < nch; c += NQ) {
        // ---- prologue: issue W1->B0; features for this chunk (16 threads) ----
        stage16k(W1, WB0, tid);
        if (tid < TC) {
            float f9[9];
#pragma unroll
            for (int u = 0; u < 9; ++u) f9[u] = 0.f;
            float wcut = 0.f;
            const int r = c * TC + tid;
            if (r < T) {
                // select r-th set bit of msk
                int rr = r, word = 0;
                while (true) {
                    const int pc = __popcll(msk[word]);
                    if (rr < pc) break;
                    rr -= pc; ++word;
                }
                unsigned long long m = msk[word];
                for (int s = 0; s < rr; ++s) m &= m - 1;
                const int p = word * 64 + (__ffsll((long long)m) - 1);
                int j, k;
                decode_pair(p, j, k);
                const float Rij = Dm[i][j], Rik = Dm[i][k], Rjk = Dm[j][k];
                const float zi = Sv[i], zj = Sv[j], zk = Sv[k];
                const float ci = (Rij*Rij + Rik*Rik - Rjk*Rjk) / fmaxf(2.f*Rij*Rik, CLIP_MIN_F);
                const float cj = (Rij*Rij + Rjk*Rjk - Rik*Rik) / fmaxf(2.f*Rij*Rjk, CLIP_MIN_F);
                const float ck = (Rik*Rik + Rjk*Rjk - Rij*Rij) / fmaxf(2.f*Rik*Rjk, CLIP_MIN_F);
                float g0 = Rij + Rik + Rjk;
                float g1 = Rij*Rik + Rij*Rjk + Rik*Rjk;
                float g2 = Rij*Rik*Rjk;
                const float gn = sqrtf(g0*g0 + g1*g1 + g2*g2) + EPS_F;
                float h0 = zi + zj + zk;
                float h1 = ci + cj + ck;
                float h2 = zi*(zj + zk) + zj*zk - ci*(cj + ck) - cj*ck;
                float h3 = zi*(cj + ck) + ci*(zj + zk) + zj*ck + cj*zk;
                float h4 = zi*(zj*zk - cj*ck) - ci*(zj*ck + cj*zk);
                float h5 = zi*(zj*ck + cj*zk) + ci*(zj*zk - cj*ck);
                const float hn = sqrtf(h0*h0 + h1*h1 + h2*h2 + h3*h3 + h4*h4 + h5*h5) + EPS_F;
                f9[0] = g0 / gn; f9[1] = g1 / gn; f9[2] = g2 / gn;
                f9[3] = h0 / hn; f9[4] = h1 / hn; f9[5] = h2 / hn;
                f9[6] = h3 / hn; f9[7] = h4 / hn; f9[8] = h5 / hn;
                const float fcij = 0.5f * cosf(PI_F * Rij / CUTOFF_F) + 0.5f;
                const float fcik = 0.5f * cosf(PI_F * Rik / CUTOFF_F) + 0.5f;
                wcut = fcij * fcik;
            }
#pragma unroll
            for (int u = 0; u < 9; ++u) Xs[u * XS + tid] = f9[u];
            wsh[tid] = wcut;
        }
        PIPE_BAR4();                      // W1 stays in flight
        // ph0: issue W2->B1; L0 (W0s)
        stage16k(W2, WB1, tid);
        compute64<9,  false>(W0s, bias0, Xs, U0, nullptr, tid);   // x_res -> U0
        PIPE_BAR4();                      // W1 done, W2 in flight
        // ph1: issue W3->B2; L1 (B0=W1, res U0)
        stage16k(W3, WB2, tid);
        compute64<64, true >(WB0, bias1, U0, U1, U0, tid);        // xb1 -> U1
        PIPE_BAR4();
        // ph2: issue W4->B0; L2 (B1=W2)
        stage16k(W4, WB0, tid);
        compute64<64, false>(WB1, bias2, U1, U2, nullptr, tid);   // x2 -> U2
        PIPE_BAR4();
        // ph3: issue W5a->B1; L3 (B2=W3)
        stage16k(W5, WB1, tid);
        compute64<64, false>(WB2, bias3, U2, U0, nullptr, tid);   // x3 -> U0
        PIPE_BAR4();
        // ph4: issue W5b->B2; L4 (B0=W4, res U1)
        stage16k(W5 + 4096, WB2, tid);
        compute64<64, true >(WB0, bias4, U0, U2, U1, tid);        // xb2 -> U2
        PIPE_BAR4();

        // ---- L5: 2 k-slices, persistent accumulators ----
        float a0[4], a1[4];
#pragma unroll
        for (int r = 0; r < 4; ++r) { a0[r] = bias5a; a1[r] = bias5b; }
        // ph5: issue W6s0->B0; L5a (B1=W5a)
        stage16k(W6, WB0, tid);
        compute5_part(WB1, U2, 0, a0, a1, tid);
        PIPE_BAR4();
        // ph6: issue W6s1->B1; L5b (B2=W5b); tanh -> U0 (lo) / U1 (hi)
        stage16k(W6 + 4096, WB1, tid);
        compute5_part(WB2, U2, 32, a0, a1, tid);
        {
            const int fo = tid & 63;
            const int xo = (tid >> 6) * 4;
            float4 y0, y1;
            y0.x = fast_tanh(a0[0]); y0.y = fast_tanh(a0[1]);
            y0.z = fast_tanh(a0[2]); y0.w = fast_tanh(a0[3]);
            y1.x = fast_tanh(a1[0]); y1.y = fast_tanh(a1[1]);
            y1.z = fast_tanh(a1[2]); y1.w = fast_tanh(a1[3]);
            *(float4*)&U0[fo * XS + xo] = y0;   // xb3 rows 0-63
            *(float4*)&U1[fo * XS + xo] = y1;   // xb3 rows 64-127
        }
        PIPE_BAR4();

        // ---- L6: 8 k-slices of 16 rows; thread = output f=tid x 16 triplets ----
        float a6[16];
#pragma unroll
        for (int r = 0; r < 16; ++r) a6[r] = bias6;
        stage16k(W6 + 2 * 4096, WB2, tid);  // ph7: issue s2->B2; s0 (B0)
        compute6_part(WB0, U0 + 0 * XS, a6, tid);
        PIPE_BAR4();
        stage16k(W6 + 3 * 4096, WB0, tid);  // ph8: issue s3->B0; s1 (B1)
        compute6_part(WB1, U0 + 16 * XS, a6, tid);
        PIPE_BAR4();
        stage16k(W6 + 4 * 4096, WB1, tid);  // ph9: issue s4->B1; s2 (B2)
        compute6_part(WB2, U0 + 32 * XS, a6, tid);
        PIPE_BAR4();
        stage16k(W6 + 5 * 4096, WB2, tid);  // ph10: issue s5->B2; s3 (B0)
        compute6_part(WB0, U0 + 48 * XS, a6, tid);
        PIPE_BAR4();
        stage16k(W6 + 6 * 4096, WB0, tid);  // ph11: issue s6->B0; s4 (B1)
        compute6_part(WB1, U1 + 0 * XS, a6, tid);
        PIPE_BAR4();
        stage16k(W6 + 7 * 4096, WB1, tid);  // ph12: issue s7->B1; s5 (B2)
        compute6_part(WB2, U1 + 16 * XS, a6, tid);
        PIPE_BAR4();
        compute6_part(WB0, U1 + 32 * XS, a6, tid);  // ph13: s6 (B0)
        PIPE_BAR0();                         // s7 (last in flight) must land
        compute6_part(WB1, U1 + 48 * XS, a6, tid);  // ph14: s7 (B1)

        // finalize: weighted tanh sum into register accumulator
#pragma unroll 4
        for (int r = 0; r < 16; ++r)
            gacc += wsh[r] * fast_tanh(a6[r]);
        __syncthreads();   // protect wsh/Xs before next chunk overwrites
    }

    gslot[tid] = gacc;     // private slot: plain store, no atomic
}

// ---------------- K3: sum NQ partials + normalize ----------------
__global__ __launch_bounds__(256) void aev_norm(
    const float* __restrict__ GAq, float* __restrict__ out)
{
    __shared__ float wred[4];
    const int tid = threadIdx.x;
    const int cell = blockIdx.x;
    float v = 0.f;
#pragma unroll
    for (int q = 0; q < NQ; ++q)
        v += GAq[(cell * NQ + q) * 256 + tid];
    float ss = v * v;
#pragma unroll
    for (int off = 32; off > 0; off >>= 1) ss += __shfl_down(ss, off);
    if ((tid & 63) == 0) wred[tid >> 6] = ss;
    __syncthreads();
    const float tot = wred[0] + wred[1] + wred[2] + wred[3];
    out[cell * 256 + tid] = v / (sqrtf(tot) + EPS_F);
}

extern "C" void kernel_launch(void* const* d_in, const int* in_sizes, int n_in,
                              void* d_out, int out_size, void* d_ws, size_t ws_size,
                              hipStream_t stream)
{
    const float* D  = (const float*)d_in[0];
    const float* S  = (const float*)d_in[1];
    const float* W0 = (const float*)d_in[2];  const float* b0 = (const float*)d_in[3];
    const float* W1 = (const float*)d_in[4];  const float* b1 = (const float*)d_in[5];
    const float* W2 = (const float*)d_in[6];  const float* b2 = (const float*)d_in[7];
    const float* W3 = (const float*)d_in[8];  const float* b3 = (const float*)d_in[9];
    const float* W4 = (const float*)d_in[10]; const float* b4 = (const float*)d_in[11];
    const float* W5 = (const float*)d_in[12]; const float* b5 = (const float*)d_in[13];
    const float* W6 = (const float*)d_in[14]; const float* b6 = (const float*)d_in[15];
    float* out = (float*)d_out;

    float* GAq = (float*)d_ws;   // [NCELL][NQ][256] partial sums

    aev_mlp<<<dim3(NCELL * NQ), dim3(256), 0, stream>>>(
        D, S, W0, b0, W1, b1, W2, b2, W3, b3, W4, b4, W5, b5, W6, b6, GAq);
    aev_norm<<<dim3(NCELL), dim3(256), 0, stream>>>(GAq, out);
}

// Round 11
// 114.701 us; speedup vs baseline: 1.1755x; 1.1755x over previous
//
#include <hip/hip_runtime.h>
#include <math.h>

#define NB 8
#define NA 32
#define NCELL 256
#define NPAIR 496
#define SLOT 496          // max triplets per cell
#define FST 10            // 9 features + weight
#define TC 16             // triplets per chunk
#define XS 20             // padded activation row stride (floats, 16B-aligned)
#define NQ 8              // chunk-slots per cell
#define CUTOFF_F 3.5f
#define EPS_F 1e-7f
#define CLIP_MIN_F 1e-10f
#define PI_F 3.14159274101257324f   // float32(np.pi)

// counted-vmcnt pipeline barrier (T4): keep the newest 4 global_load_lds in
// flight across the barrier; drains the oldest 4 = the slice consumed next.
#define PIPE_BAR4() do { \
    asm volatile("s_waitcnt lgkmcnt(0) vmcnt(4)" ::: "memory"); \
    __builtin_amdgcn_s_barrier(); \
    __builtin_amdgcn_sched_barrier(0); \
} while (0)
#define PIPE_BAR0() do { \
    asm volatile("s_waitcnt lgkmcnt(0) vmcnt(0)" ::: "memory"); \
    __builtin_amdgcn_s_barrier(); \
    __builtin_amdgcn_sched_barrier(0); \
} while (0)

// fast tanh: (e^2ax-1)/(e^2ax+1) with sign reattach; ~1e-7 abs err
__device__ __forceinline__ float fast_tanh(float x) {
    const float ax = fabsf(x);
    const float t = exp2f(fminf(2.8853900817779268f * ax, 30.0f)); // e^{2ax}
    const float r = (t - 1.0f) * __builtin_amdgcn_rcpf(t + 1.0f);
    return __int_as_float((__float_as_int(x) & 0x80000000) | __float_as_int(r));
}

// ---------------- K1: compact active triplets, compute features ----------------
__global__ __launch_bounds__(256) void aev_feat(
    const float* __restrict__ D, const float* __restrict__ S,
    float* __restrict__ feat, int* __restrict__ count, float* __restrict__ GA)
{
    __shared__ float Dm[NA][NA];
    __shared__ float Sv[NA];
    __shared__ int s_T;
    const int tid = threadIdx.x;
    const int cell = blockIdx.x;
    const int b = cell >> 5, i = cell & 31;

    for (int idx = tid; idx < NA * NA; idx += 256)
        ((float*)Dm)[idx] = D[b * NA * NA + idx];
    if (tid < NA) Sv[tid] = S[b * NA + tid];
    if (tid == 0) s_T = 0;
    GA[cell * 256 + tid] = 0.f;
    __syncthreads();

    for (int p = tid; p < NPAIR; p += 256) {
        int rem = p, j = 0;
        while (rem >= 31 - j) { rem -= 31 - j; ++j; }
        const int k = j + 1 + rem;
        const float dij = Dm[i][j], dik = Dm[i][k];
        if (dij < CUTOFF_F && dij != 0.f && dik < CUTOFF_F && dik != 0.f) {
            const int slot = atomicAdd(&s_T, 1);
            const float Rij = dij, Rik = dik, Rjk = Dm[j][k];
            const float zi = Sv[i], zj = Sv[j], zk = Sv[k];
            const float ci = (Rij*Rij + Rik*Rik - Rjk*Rjk) / fmaxf(2.f*Rij*Rik, CLIP_MIN_F);
            const float cj = (Rij*Rij + Rjk*Rjk - Rik*Rik) / fmaxf(2.f*Rij*Rjk, CLIP_MIN_F);
            const float ck = (Rik*Rik + Rjk*Rjk - Rij*Rij) / fmaxf(2.f*Rik*Rjk, CLIP_MIN_F);
            float g0 = Rij + Rik + Rjk;
            float g1 = Rij*Rik + Rij*Rjk + Rik*Rjk;
            float g2 = Rij*Rik*Rjk;
            const float gn = sqrtf(g0*g0 + g1*g1 + g2*g2) + EPS_F;
            float h0 = zi + zj + zk;
            float h1 = ci + cj + ck;
            float h2 = zi*(zj + zk) + zj*zk - ci*(cj + ck) - cj*ck;
            float h3 = zi*(cj + ck) + ci*(zj + zk) + zj*ck + cj*zk;
            float h4 = zi*(zj*zk - cj*ck) - ci*(zj*ck + cj*zk);
            float h5 = zi*(zj*ck + cj*zk) + ci*(zj*zk - cj*ck);
            const float hn = sqrtf(h0*h0 + h1*h1 + h2*h2 + h3*h3 + h4*h4 + h5*h5) + EPS_F;
            const float fcij = 0.5f * cosf(PI_F * Rij / CUTOFF_F) + 0.5f;
            const float fcik = 0.5f * cosf(PI_F * Rik / CUTOFF_F) + 0.5f;
            float* fp = &feat[(cell * SLOT + slot) * FST];
            fp[0] = g0 / gn; fp[1] = g1 / gn; fp[2] = g2 / gn;
            fp[3] = h0 / hn; fp[4] = h1 / hn; fp[5] = h2 / hn;
            fp[6] = h3 / hn; fp[7] = h4 / hn; fp[8] = h5 / hn;
            fp[9] = fcij * fcik;
        }
    }
    __syncthreads();
    if (tid == 0) count[cell] = s_T;
}

// -------- async global->LDS staging (no VGPR payload) --------
__device__ __forceinline__ void cp_async16(const float* g, float* l) {
    __builtin_amdgcn_global_load_lds(
        (const __attribute__((address_space(1))) unsigned int*)g,
        (__attribute__((address_space(3))) unsigned int*)l, 16, 0, 0);
}

// stage one 4096-float (16KB) slice: 4 issues/thread (vmcnt +4 per wave)
__device__ __forceinline__ void stage16k(const float* __restrict__ g,
                                         float* __restrict__ buf, int tid) {
    const int lane = tid & 63, w = tid >> 6;
#pragma unroll
    for (int r = 0; r < 4; ++r) {
        const int off = (w * 4 + r) * 256;
        cp_async16(g + off + lane * 4, buf + off);   // LDS base wave-uniform
    }
}

// -------- layer computes (weights from LDS, bias from register) --------
// 64-out layer: thread = 1 feature x 4 triplets. BOUNDED unroll — full unroll
// lets the scheduler hoist all ds_reads and blow the VGPR file (r4/r5 bug).
template<int K, bool RES>
__device__ __forceinline__ void compute64(
    const float* __restrict__ Wl, float bb,
    const float* __restrict__ X, float* __restrict__ Y,
    const float* __restrict__ R, int tid)
{
    const int fi = tid & 63;
    const int xo = (tid >> 6) * 4;       // wave-uniform -> broadcast reads
    float a0 = bb, a1 = bb, a2 = bb, a3 = bb;
#pragma unroll 4
    for (int k = 0; k < K; ++k) {
        const float4 xv = *(const float4*)&X[k * XS + xo];
        const float w = Wl[k * 64 + fi];
        a0 += xv.x * w; a1 += xv.y * w; a2 += xv.z * w; a3 += xv.w * w;
    }
    float4 y;
    y.x = fast_tanh(a0); y.y = fast_tanh(a1); y.z = fast_tanh(a2); y.w = fast_tanh(a3);
    if (RES) {
        const float4 r = *(const float4*)&R[fi * XS + xo];
        y.x += r.x; y.y += r.y; y.z += r.z; y.w += r.w;
    }
    *(float4*)&Y[fi * XS + xo] = y;
}

// 64->128 layer, one 32-row k-slice. Thread = 4 features x 2 triplets
// (f = (tid&31)*4, t = (tid>>5)*2): per k 1 b128 wt + 1 b64 act = 2 LDS
// instr / 8 FMA (was 3/8) — LDS-issue is the kernel's bottleneck.
__device__ __forceinline__ void compute5_part(
    const float* __restrict__ Wl /*32 rows x 128*/, const float* __restrict__ X,
    int k0, float (&a)[4][2], int tid)
{
    const int f = (tid & 31) * 4;
    const int t = (tid >> 5) * 2;
#pragma unroll 4
    for (int k = 0; k < 32; ++k) {
        const float4 wv = *(const float4*)&Wl[k * 128 + f];
        const float2 xv = *(const float2*)&X[(k0 + k) * XS + t];
        a[0][0] += wv.x * xv.x; a[0][1] += wv.x * xv.y;
        a[1][0] += wv.y * xv.x; a[1][1] += wv.y * xv.y;
        a[2][0] += wv.z * xv.x; a[2][1] += wv.z * xv.y;
        a[3][0] += wv.w * xv.x; a[3][1] += wv.w * xv.y;
    }
}

// 128->256 layer, one 16-row k-slice. Thread = 4 features x 4 triplets;
// wave owns a disjoint 64-feature quarter (f = (tid>>6)*64 + (tid&15)*4,
// t = ((tid>>4)&3)*4): per k 1 b128 wt + 1 b128 act = 2 LDS instr / 16 FMA
// (was 5/16). Bias lives in the acc init (each (f,t) owned by ONE thread).
__device__ __forceinline__ void compute6_part(
    const float* __restrict__ Wl /*16 rows x 256*/, const float* __restrict__ X,
    float (&c)[4][4], int f, int t)
{
#pragma unroll 2
    for (int k = 0; k < 16; ++k) {
        const float4 wv = *(const float4*)&Wl[k * 256 + f];
        const float4 xv = *(const float4*)&X[k * XS + t];
        c[0][0] += wv.x * xv.x; c[0][1] += wv.x * xv.y; c[0][2] += wv.x * xv.z; c[0][3] += wv.x * xv.w;
        c[1][0] += wv.y * xv.x; c[1][1] += wv.y * xv.y; c[1][2] += wv.y * xv.z; c[1][3] += wv.y * xv.w;
        c[2][0] += wv.z * xv.x; c[2][1] += wv.z * xv.y; c[2][2] += wv.z * xv.z; c[2][3] += wv.z * xv.w;
        c[3][0] += wv.w * xv.x; c[3][1] += wv.w * xv.y; c[3][2] += wv.w * xv.z; c[3][3] += wv.w * xv.w;
    }
}

// ---------------- K2: 3-buffer rotation with counted-vmcnt barriers ----------
__global__ __launch_bounds__(256) void aev_mlp(
    const float* __restrict__ feat, const int* __restrict__ count,
    const float* __restrict__ W0, const float* __restrict__ b0,
    const float* __restrict__ W1, const float* __restrict__ b1,
    const float* __restrict__ W2, const float* __restrict__ b2,
    const float* __restrict__ W3, const float* __restrict__ b3,
    const float* __restrict__ W4, const float* __restrict__ b4,
    const float* __restrict__ W5, const float* __restrict__ b5,
    const float* __restrict__ W6, const float* __restrict__ b6,
    float* __restrict__ GA)
{
    __shared__ __align__(16) float WB0[4096];
    __shared__ __align__(16) float WB1[4096];
    __shared__ __align__(16) float WB2[4096];
    __shared__ __align__(16) float W0s[576];
    __shared__ __align__(16) float Xs[9 * XS];
    __shared__ __align__(16) float U0[64 * XS];
    __shared__ __align__(16) float U1[64 * XS];
    __shared__ __align__(16) float U2[64 * XS];   // xb2; reused as GA partial buf
    __shared__ float wsh[TC];

    const int tid = threadIdx.x;
    const int cell = blockIdx.x & 255;   // q-major: siblings on different CUs
    const int q = blockIdx.x >> 8;
    const int T = count[cell];
    const int nch = (T + TC - 1) / TC;
    if (q >= nch) return;                // block-uniform exit (no barriers yet)

    // loop-invariant per-thread biases (registers, not LDS)
    const int fi64 = tid & 63;
    const float bias0 = b0[fi64];
    const float bias1 = b1[fi64];
    const float bias2 = b2[fi64];
    const float bias3 = b3[fi64];
    const float bias4 = b4[fi64];
    const int f5 = (tid & 31) * 4;            // L5 feature base
    const int t5 = (tid >> 5) * 2;            // L5 triplet base
    const float4 bias5v = *(const float4*)&b5[f5];
    const int f6 = (tid >> 6) * 64 + (tid & 15) * 4;   // L6 feature base
    const int t6 = ((tid >> 4) & 3) * 4;               // L6 triplet base
    const float4 bias6v = *(const float4*)&b6[f6];

    // W0 (2.3KB) staged once per block (covered by first PIPE_BAR4)
    if (tid < 144) ((float4*)W0s)[tid] = ((const float4*)W0)[tid];

    float gacc = 0.f;

    for (int c = q; c < nch; c += NQ) {
        const int t0 = c * TC;

        // ---- prologue: issue W1->B0; features for this chunk ----
        stage16k(W1, WB0, tid);
        if (tid < TC * FST) {   // contiguous 160 floats
            const int t = tid / FST, qf = tid % FST;
            const int slot = t0 + t;
            const float v = (slot < T) ? feat[(cell * SLOT + t0) * FST + tid] : 0.f;
            if (qf == 9) wsh[t] = v; else Xs[qf * XS + t] = v;
        }
        PIPE_BAR4();                      // W1 stays in flight
        // ph0: issue W2->B1; L0 (W0s)
        stage16k(W2, WB1, tid);
        compute64<9,  false>(W0s, bias0, Xs, U0, nullptr, tid);   // x_res -> U0
        PIPE_BAR4();                      // W1 done, W2 in flight
        // ph1: issue W3->B2; L1 (B0=W1, res U0)
        stage16k(W3, WB2, tid);
        compute64<64, true >(WB0, bias1, U0, U1, U0, tid);        // xb1 -> U1
        PIPE_BAR4();
        // ph2: issue W4->B0; L2 (B1=W2)
        stage16k(W4, WB0, tid);
        compute64<64, false>(WB1, bias2, U1, U2, nullptr, tid);   // x2 -> U2
        PIPE_BAR4();
        // ph3: issue W5a->B1; L3 (B2=W3)
        stage16k(W5, WB1, tid);
        compute64<64, false>(WB2, bias3, U2, U0, nullptr, tid);   // x3 -> U0
        PIPE_BAR4();
        // ph4: issue W5b->B2; L4 (B0=W4, res U1)
        stage16k(W5 + 4096, WB2, tid);
        compute64<64, true >(WB0, bias4, U0, U2, U1, tid);        // xb2 -> U2
        PIPE_BAR4();

        // ---- L5: 2 k-slices, persistent 4x2 accumulator ----
        float a5[4][2];
#pragma unroll
        for (int i = 0; i < 4; ++i) {
            const float bi = (i == 0) ? bias5v.x : (i == 1) ? bias5v.y
                           : (i == 2) ? bias5v.z : bias5v.w;
            a5[i][0] = bi; a5[i][1] = bi;
        }
        // ph5: issue W6s0->B0; L5a (B1=W5a)
        stage16k(W6, WB0, tid);
        compute5_part(WB1, U2, 0, a5, tid);
        PIPE_BAR4();
        // ph6: issue W6s1->B1; L5b (B2=W5b); tanh -> U0 (rows 0-63) / U1 (64-127)
        stage16k(W6 + 4096, WB1, tid);
        compute5_part(WB2, U2, 32, a5, tid);
        {
            float* base = (f5 < 64) ? U0 : U1;       // uniform per thread
            const int fr = f5 & 63;
#pragma unroll
            for (int i = 0; i < 4; ++i) {
                float2 y;
                y.x = fast_tanh(a5[i][0]); y.y = fast_tanh(a5[i][1]);
                *(float2*)&base[(fr + i) * XS + t5] = y;
            }
        }
        PIPE_BAR4();

        // ---- L6: 8 k-slices of 16 rows; thread = 4 feat x 4 trip ----
        float c6[4][4];
#pragma unroll
        for (int i = 0; i < 4; ++i) {
            const float bi = (i == 0) ? bias6v.x : (i == 1) ? bias6v.y
                           : (i == 2) ? bias6v.z : bias6v.w;
#pragma unroll
            for (int j = 0; j < 4; ++j) c6[i][j] = bi;
        }
        stage16k(W6 + 2 * 4096, WB2, tid);  // ph7: issue s2->B2; s0 (B0)
        compute6_part(WB0, U0 + 0 * XS, c6, f6, t6);
        PIPE_BAR4();
        stage16k(W6 + 3 * 4096, WB0, tid);  // ph8: issue s3->B0; s1 (B1)
        compute6_part(WB1, U0 + 16 * XS, c6, f6, t6);
        PIPE_BAR4();
        stage16k(W6 + 4 * 4096, WB1, tid);  // ph9: issue s4->B1; s2 (B2)
        compute6_part(WB2, U0 + 32 * XS, c6, f6, t6);
        PIPE_BAR4();
        stage16k(W6 + 5 * 4096, WB2, tid);  // ph10: issue s5->B2; s3 (B0)
        compute6_part(WB0, U0 + 48 * XS, c6, f6, t6);
        PIPE_BAR4();
        stage16k(W6 + 6 * 4096, WB0, tid);  // ph11: issue s6->B0; s4 (B1)
        compute6_part(WB1, U1 + 0 * XS, c6, f6, t6);
        PIPE_BAR4();
        stage16k(W6 + 7 * 4096, WB1, tid);  // ph12: issue s7->B1; s5 (B2)
        compute6_part(WB2, U1 + 16 * XS, c6, f6, t6);
        PIPE_BAR4();
        compute6_part(WB0, U1 + 32 * XS, c6, f6, t6);  // ph13: s6 (B0)
        PIPE_BAR0();                         // s7 (last in flight) must land
        compute6_part(WB1, U1 + 48 * XS, c6, f6, t6);  // ph14: s7 (B1)

        // ---- finalize: weighted tanh partial per thread, cross-tg reduce ----
        {
            const float4 wv4 = *(const float4*)&wsh[t6];
            float4 s;
            s.x = wv4.x * fast_tanh(c6[0][0]) + wv4.y * fast_tanh(c6[0][1])
                + wv4.z * fast_tanh(c6[0][2]) + wv4.w * fast_tanh(c6[0][3]);
            s.y = wv4.x * fast_tanh(c6[1][0]) + wv4.y * fast_tanh(c6[1][1])
                + wv4.z * fast_tanh(c6[1][2]) + wv4.w * fast_tanh(c6[1][3]);
            s.z = wv4.x * fast_tanh(c6[2][0]) + wv4.y * fast_tanh(c6[2][1])
                + wv4.z * fast_tanh(c6[2][2]) + wv4.w * fast_tanh(c6[2][3]);
            s.w = wv4.x * fast_tanh(c6[3][0]) + wv4.y * fast_tanh(c6[3][1])
                + wv4.z * fast_tanh(c6[3][2]) + wv4.w * fast_tanh(c6[3][3]);
            // Pg[fgrp][tg][4]: fgrp = f6>>2 in [0,64), tg = t6>>2 — fits U2
            *(float4*)&U2[((f6 >> 2) << 4) + (t6 & 12)] = s;
        }
        __syncthreads();
        gacc += U2[(tid >> 2) * 16 + 0  + (tid & 3)]
              + U2[(tid >> 2) * 16 + 4  + (tid & 3)]
              + U2[(tid >> 2) * 16 + 8  + (tid & 3)]
              + U2[(tid >> 2) * 16 + 12 + (tid & 3)];
        __syncthreads();   // protect wsh/Xs/U2 before next chunk overwrites
    }

    atomicAdd(&GA[cell * 256 + tid], gacc);
}

// ---------------- K3: normalize ----------------
__global__ __launch_bounds__(256) void aev_norm(
    const float* __restrict__ GA, float* __restrict__ out)
{
    __shared__ float wred[4];
    const int tid = threadIdx.x;
    const int cell = blockIdx.x;
    const float v = GA[cell * 256 + tid];
    float ss = v * v;
#pragma unroll
    for (int off = 32; off > 0; off >>= 1) ss += __shfl_down(ss, off);
    if ((tid & 63) == 0) wred[tid >> 6] = ss;
    __syncthreads();
    const float tot = wred[0] + wred[1] + wred[2] + wred[3];
    out[cell * 256 + tid] = v / (sqrtf(tot) + EPS_F);
}

extern "C" void kernel_launch(void* const* d_in, const int* in_sizes, int n_in,
                              void* d_out, int out_size, void* d_ws, size_t ws_size,
                              hipStream_t stream)
{
    const float* D  = (const float*)d_in[0];
    const float* S  = (const float*)d_in[1];
    const float* W0 = (const float*)d_in[2];  const float* b0 = (const float*)d_in[3];
    const float* W1 = (const float*)d_in[4];  const float* b1 = (const float*)d_in[5];
    const float* W2 = (const float*)d_in[6];  const float* b2 = (const float*)d_in[7];
    const float* W3 = (const float*)d_in[8];  const float* b3 = (const float*)d_in[9];
    const float* W4 = (const float*)d_in[10]; const float* b4 = (const float*)d_in[11];
    const float* W5 = (const float*)d_in[12]; const float* b5 = (const float*)d_in[13];
    const float* W6 = (const float*)d_in[14]; const float* b6 = (const float*)d_in[15];
    float* out = (float*)d_out;

    float* feat  = (float*)d_ws;                        // 256*496*10 floats
    int*   count = (int*)(feat + NCELL * SLOT * FST);   // 256 ints
    float* GA    = (float*)(count + 256);               // 256*256 floats

    aev_feat<<<dim3(NCELL), dim3(256), 0, stream>>>(D, S, feat, count, GA);
    aev_mlp<<<dim3(NCELL * NQ), dim3(256), 0, stream>>>(
        feat, count, W0, b0, W1, b1, W2, b2, W3, b3, W4, b4, W5, b5, W6, b6, GA);
    aev_norm<<<dim3(NCELL), dim3(256), 0, stream>>>(GA, out);
}